// Round 5
// baseline (358.812 us; speedup 1.0000x reference)
//
#include <hip/hip_runtime.h>

typedef float __attribute__((ext_vector_type(4))) f32x4;

#define BB 256
#define NN 196
#define DD 768
#define PP 32
#define TOPK 5
#define NROW 216           /* 20 + 196 */

/* fp32 element offsets in d_out (flat concat in return order) */
#define OUT0_ELTS (BB * NROW * DD)   /* 42467328 */
#define RS_OFF    OUT0_ELTS
#define SIM_OFF   (OUT0_ELTS + 1)
#define IDX_OFF   (OUT0_ELTS + 1 + BB * PP)

/* ws layout (byte offsets) */
#define WS_PEMB   0                          /* 128*768 fp32 = 393216 B */

/* ---- Kernel 1: streaming copy + partial column sums + patch embed.
   Blocks 0..31   : patch-embed prompt p=blk (4 positions x 768 channels,
                    one channel per thread; patches in LDS). Runs hidden
                    under the copy blocks' HBM streaming (VALU vs HBM).
   Blocks 32..543 : 2 blocks per batch b. Each streams 98 x-rows ->
                    out0 rows [20..216) via NT load/store (no mid-loop
                    barriers), reduces its partial column sums to 768
                    floats, and parks them in out0 scratch row h of
                    batch b (rows 0..1 -- overwritten by gather later).
   2 blocks/CU so epilogues overlap other blocks' streaming. */
__global__ __launch_bounds__(768, 6) void k_copy(
    const float* __restrict__ x, const float* __restrict__ prompt,
    const float* __restrict__ cw, const float* __restrict__ cb,
    float* __restrict__ pemb, float* __restrict__ out)
{
    const int t = threadIdx.x;
    __shared__ f32x4 shbuf4[768];            /* 12 KB: comb | patch */

    if (blockIdx.x < PP) {
        /* ---- patch embed, one prompt per block ---- */
        const int p = blockIdx.x;
        float* patch = (float*)shbuf4;       /* [4][768]: pos-major */
        for (int idx = t; idx < 4 * DD; idx += 768) {
            const int j = idx / DD, kk = idx - j * DD;   /* j = position */
            const int ch = kk >> 8, rem = kk & 255;
            const int kh = rem >> 4, kw = rem & 15;
            patch[idx] = prompt[(size_t)p * 3072 + (size_t)ch * 1024
                                + ((j >> 1) * 16 + kh) * 32 + (j & 1) * 16 + kw];
        }
        __syncthreads();
        const float4* wrow = (const float4*)(cw + (size_t)t * DD);
        const float4* q0 = (const float4*)(patch);
        const float4* q1 = (const float4*)(patch + DD);
        const float4* q2 = (const float4*)(patch + 2 * DD);
        const float4* q3 = (const float4*)(patch + 3 * DD);
        float a0 = 0.f, a1 = 0.f, a2 = 0.f, a3 = 0.f;
#pragma unroll 4
        for (int kk = 0; kk < 192; ++kk) {
            const float4 w = wrow[kk];
            const float4 v0 = q0[kk], v1 = q1[kk], v2 = q2[kk], v3 = q3[kk];
            a0 += v0.x * w.x + v0.y * w.y + v0.z * w.z + v0.w * w.w;
            a1 += v1.x * w.x + v1.y * w.y + v1.z * w.z + v1.w * w.w;
            a2 += v2.x * w.x + v2.y * w.y + v2.z * w.z + v2.w * w.w;
            a3 += v3.x * w.x + v3.y * w.y + v3.z * w.z + v3.w * w.w;
        }
        const float bias = cb[t];
        float* pe = pemb + (size_t)(4 * p) * DD + t;
        pe[0]      = a0 + bias;
        pe[DD]     = a1 + bias;
        pe[2 * DD] = a2 + bias;
        pe[3 * DD] = a3 + bias;
        return;
    }

    /* ---- streaming copy: half h of batch b ---- */
    const int blk = blockIdx.x - PP;
    const int b = blk >> 1, h = blk & 1;
    const int g = t / 192, c = t - g * 192;       /* wave-uniform g */
    const int r0 = h * 98;                        /* 98 rows per half */
    const f32x4* xb4 = (const f32x4*)(x + (size_t)b * (NN * DD));
    f32x4* ob4 = (f32x4*)(out + (size_t)b * (NROW * DD) + 20 * DD);
    f32x4 s = (f32x4)(0.f);
    /* rows r0 + g + 4*i, i = 0..24 (i=24 masked off for g>=2) */
#pragma unroll
    for (int o = 0; o < 5; ++o) {
        f32x4 vv[5];
#pragma unroll
        for (int i = 0; i < 5; ++i) {
            const int r = g + 4 * (o * 5 + i);
            if (r < 98)
                vv[i] = __builtin_nontemporal_load(xb4 + (size_t)(r0 + r) * 192 + c);
        }
#pragma unroll
        for (int i = 0; i < 5; ++i) {
            const int r = g + 4 * (o * 5 + i);
            if (r < 98) {
                s += vv[i];
                __builtin_nontemporal_store(vv[i], ob4 + (size_t)(r0 + r) * 192 + c);
            }
        }
    }
    /* reduce 4 row-groups -> 768 partial column sums, park in scratch
       row h of this batch's out0 (rows 0..1, overwritten by gather) */
    shbuf4[g * 192 + c] = s;
    __syncthreads();
    if (t < 192) {
        const f32x4 ps = shbuf4[t] + shbuf4[192 + t] + shbuf4[384 + t] + shbuf4[576 + t];
        ((f32x4*)(out + (size_t)b * (NROW * DD) + (size_t)h * DD))[t] = ps;
    }
}

/* ---- Kernel 2: per-batch tail. Read the two partial-sum rows, mean,
   L2-norm, 32 sim dots (in-loop pkey normalization), wave-parallel
   top-5, sim/idx/reduce_sim writes, gather 20 prompt-embed rows. */
__global__ __launch_bounds__(768) void k_tail(const float* __restrict__ pkey,
                                              const float* __restrict__ pemb,
                                              float* __restrict__ out) {
    const int b = blockIdx.x;
    const int t = threadIdx.x;
    __shared__ float xm[768];
    __shared__ float sims[PP];
    __shared__ float wred[12];
    __shared__ float rsh;
    __shared__ int lidx[TOPK];

    const float* sc = out + (size_t)b * (NROW * DD);      /* scratch rows 0,1 */
    const float xmv = (sc[t] + sc[DD + t]) * (1.0f / NN);
    xm[t] = xmv;
    float sq = xmv * xmv;
#pragma unroll
    for (int off = 32; off; off >>= 1) sq += __shfl_down(sq, off);
    if ((t & 63) == 0) wred[t >> 6] = sq;
    __syncthreads();
    if (t == 0) {
        float tot = 0.f;
        for (int i = 0; i < 12; ++i) tot += wred[i];
        rsh = rsqrtf(fmaxf(tot, 1e-12f));
    }
    __syncthreads();
    const float r = rsh;

    /* ---- 32 sim dots, 16 threads per prompt, pkey normalized in-loop ---- */
    if (t < 512) {
        const int p = t >> 4, sub = t & 15;
        const float* pr = pkey + (size_t)p * DD;
        float acc = 0.f, nrm = 0.f;
#pragma unroll 8
        for (int j = 0; j < 48; ++j) {
            const int k = sub + (j << 4);
            const float pk = pr[k];
            acc += xm[k] * pk;
            nrm += pk * pk;
        }
        acc += __shfl_down(acc, 8, 16);  nrm += __shfl_down(nrm, 8, 16);
        acc += __shfl_down(acc, 4, 16);  nrm += __shfl_down(nrm, 4, 16);
        acc += __shfl_down(acc, 2, 16);  nrm += __shfl_down(nrm, 2, 16);
        acc += __shfl_down(acc, 1, 16);  nrm += __shfl_down(nrm, 1, 16);
        if (sub == 0) {
            const float sv = acc * rsqrtf(fmaxf(nrm, 1e-12f)) * r;
            sims[p] = sv;
            out[SIM_OFF + b * PP + p] = sv;
        }
    }
    __syncthreads();

    /* ---- wave-parallel top-5 on wave 0 (tie-break: lowest index) ---- */
    if (t < 64) {
        float v = (t < PP) ? sims[t] : -1e30f;
        float rsum = 0.f;
#pragma unroll
        for (int k = 0; k < TOPK; ++k) {
            float bv = v; int bbi = t;
#pragma unroll
            for (int off = 32; off; off >>= 1) {
                const float ov = __shfl_xor(bv, off);
                const int   oi = __shfl_xor(bbi, off);
                if (ov > bv || (ov == bv && oi < bbi)) { bv = ov; bbi = oi; }
            }
            if (t == 0) {
                lidx[k] = bbi;
                out[IDX_OFF + b * TOPK + k] = (float)bbi;
                rsum += bv;
            }
            if (t == bbi) v = -1e30f;
        }
        if (t == 0) atomicAdd(&out[RS_OFF], rsum * (1.0f / BB));
    }
    __syncthreads();

    /* ---- gather 20 prompt-embed rows into out0[0..20) (overwrites scratch) ---- */
    f32x4* dst = (f32x4*)(out + (size_t)b * (NROW * DD));
    const f32x4* src = (const f32x4*)pemb;            /* 192 f32x4 per row */
    for (int v = t; v < 20 * 192; v += 768) {
        const int row = v / 192;
        const int off = v - row * 192;
        const int srow = lidx[row >> 2] * 4 + (row & 3);
        __builtin_nontemporal_store(src[srow * 192 + off], dst + row * 192 + off);
    }
}

extern "C" void kernel_launch(void* const* d_in, const int* in_sizes, int n_in,
                              void* d_out, int out_size, void* d_ws, size_t ws_size,
                              hipStream_t stream) {
    const float* x      = (const float*)d_in[0];   /* x_embed   (256,196,768) fp32 */
    const float* prompt = (const float*)d_in[1];   /* prompt    (32,3,32,32)  fp32 */
    const float* pkey   = (const float*)d_in[2];   /* prompt_key(32,768)      fp32 */
    const float* cw     = (const float*)d_in[3];   /* conv_w    (768,3,16,16) fp32 */
    const float* cb     = (const float*)d_in[4];   /* conv_b    (768,)        fp32 */
    float* out = (float*)d_out;
    char* ws = (char*)d_ws;

    float* pemb = (float*)(ws + WS_PEMB);

    /* zero the reduce_sim accumulator (stream-ordered, graph-capturable) */
    hipMemsetAsync(out + RS_OFF, 0, sizeof(float), stream);
    k_copy<<<PP + 2 * BB, 768, 0, stream>>>(x, prompt, cw, cb, pemb, out);
    k_tail<<<BB, 768, 0, stream>>>(pkey, pemb, out);
}